// Round 14
// baseline (237.901 us; speedup 1.0000x reference)
//
#include <hip/hip_runtime.h>
#include <hip/hip_bf16.h>

typedef __attribute__((ext_vector_type(8))) unsigned short ushort8;
typedef __attribute__((ext_vector_type(4))) unsigned short bf16x4;
typedef __attribute__((ext_vector_type(8))) short short8;
typedef __attribute__((ext_vector_type(4))) float f32x4;
typedef __attribute__((ext_vector_type(2))) unsigned long long u64x2;

#define DEV __device__ __forceinline__

DEV unsigned short f2bf(float f) {
    unsigned u = __builtin_bit_cast(unsigned, f);
    return (unsigned short)((u + 0x7fffu + ((u >> 16) & 1u)) >> 16);
}
DEV float bf2f(unsigned short h) {
    unsigned u = ((unsigned)h) << 16;
    return __builtin_bit_cast(float, u);
}
DEV float wred(float v) {
#pragma unroll
    for (int m = 32; m > 0; m >>= 1) v += __shfl_xor(v, m, 64);
    return v;
}

constexpr int N_ = 512, D_ = 128, R_ = 512;
constexpr long NN2 = (long)N_ * N_;          // 262144
constexpr int PSTR = 520;                    // padded panel row stride (ushorts)
constexpr int USTR = 136;                    // padded uLds row stride

// async global->LDS, 16B per lane. LDS dest = wave-uniform base + lane*16.
// GLOBAL source is per-lane -> gather-staging works.
DEV void gll16(const void* g, void* l) {
    __builtin_amdgcn_global_load_lds(
        (const __attribute__((address_space(1))) unsigned*)g,
        (__attribute__((address_space(3))) unsigned*)l, 16, 0, 0);
}

// ---------------- fused front: gather_app | gather_x | wT | rtab->bf16 ----------------

__global__ __launch_bounds__(256) void k_front(const int* __restrict__ recd,
                                               const float* __restrict__ rtab,
                                               const int* __restrict__ seq,
                                               const float* __restrict__ etab,
                                               const float* __restrict__ w1,
                                               const float* __restrict__ w2,
                                               float* __restrict__ out,
                                               unsigned short* __restrict__ x,
                                               unsigned short* __restrict__ wT,
                                               unsigned short* __restrict__ rtb,
                                               float* __restrict__ rnorm) {
    int bid = blockIdx.x, tid = threadIdx.x;
    if (bid < 16384) {                       // ---- gather_app: out cols 128..639 + rnorm ----
        int lane = tid & 63, w = tid >> 6;
        long r = (long)bid * 4 + w;
        int tok = recd[r];
        const float* src = rtab + (long)tok * R_;
        int j = lane * 8;
        float4 v0 = *(const float4*)(src + j);
        float4 v1 = *(const float4*)(src + j + 4);
        float ssq = v0.x*v0.x + v0.y*v0.y + v0.z*v0.z + v0.w*v0.w
                  + v1.x*v1.x + v1.y*v1.y + v1.z*v1.z + v1.w*v1.w;
        ssq = wred(ssq);
        float* o = out + r * 640 + 128 + j;
        *(float4*)o = v0;
        *(float4*)(o + 4) = v1;
        if (lane == 0) rnorm[r] = 1.0f / fmaxf(sqrtf(ssq), 1e-12f);
    } else if (bid < 20480) {                // ---- gather_x ----
        long e8 = ((long)(bid - 16384) * 256 + tid) * 8;
        long r = e8 >> 7;
        int d0 = (int)(e8 & 127);
        int tok = seq[r];
        const float* src = etab + (long)tok * D_ + d0;
        float4 v0 = *(const float4*)src, v1 = *(const float4*)(src + 4);
        ushort8 u;
        u[0]=f2bf(v0.x); u[1]=f2bf(v0.y); u[2]=f2bf(v0.z); u[3]=f2bf(v0.w);
        u[4]=f2bf(v1.x); u[5]=f2bf(v1.y); u[6]=f2bf(v1.z); u[7]=f2bf(v1.w);
        *(ushort8*)(x + e8) = u;
    } else if (bid < 20864) {                // ---- wT (folded weights) ----
        int o = (bid - 20480) * 256 + tid;   // < 98304
        int l = o / 49152;
        int rr = o - l * 49152;
        int mat = rr >> 14;
        int e2 = rr & 16383;
        int e = e2 >> 7, d = e2 & 127;
        const float* w = l ? w2 : w1;
        float v;
        if (mat == 0)      v = w[d * 128 + e] - w[32768 + d * 128 + e];
        else if (mat == 1) v = w[16384 + d * 128 + e];
        else               v = 2.0f * w[32768 + d * 128 + e];
        wT[o] = f2bf(v);
    } else {                                 // ---- rtab -> bf16 copy (5000x512) ----
        long e8 = ((long)(bid - 20864) * 256 + tid) * 8;   // < 2,560,000
        float4 v0 = *(const float4*)(rtab + e8), v1 = *(const float4*)(rtab + e8 + 4);
        ushort8 u;
        u[0]=f2bf(v0.x); u[1]=f2bf(v0.y); u[2]=f2bf(v0.z); u[3]=f2bf(v0.w);
        u[4]=f2bf(v1.x); u[5]=f2bf(v1.y); u[6]=f2bf(v1.z); u[7]=f2bf(v1.w);
        *(ushort8*)(rtb + e8) = u;
    }
}

// ---------------- staging helpers (512-thread blocks) ----------------

// 256 rows x 64 cols, ld=128, dst rowstride 64
DEV void stageA256(const unsigned short* base, int k0, unsigned short* dst, int tid) {
    int w = tid >> 6;
#pragma unroll
    for (int i = 0; i < 4; ++i) {
        int u = i * 512 + tid;
        int r = u >> 3, c = (u & 7) * 8;
        gll16(base + (long)r * 128 + k0 + c, dst + (i * 64 + w * 8) * 64);
    }
}

// 128 rows x 64 cols, ld=128, dst rowstride 64
DEV void stageB128(const unsigned short* base, int k0, unsigned short* dst, int tid) {
    int w = tid >> 6;
#pragma unroll
    for (int i = 0; i < 2; ++i) {
        int u = i * 512 + tid;
        int r = u >> 3, c = (u & 7) * 8;
        gll16(base + (long)r * 128 + k0 + c, dst + (i * 64 + w * 8) * 64);
    }
}

// ---------------- adjacency: 256x256 tiles, 3 per batch, gather-staged panels ----------------
// A_ij = dot(raw_i, raw_j) * rn_i * rn_j ; tiles (0,0),(0,1),(1,1); off-diag mirrored.
// grid 384: xcd = g&7, q = g>>3 (0..47); b = xcd + 8*(q/3); t = q%3.

__global__ __launch_bounds__(512) void k_adj(const unsigned short* __restrict__ rtb,
                                             const int* __restrict__ recd,
                                             const float* __restrict__ rnorm,
                                             unsigned short* __restrict__ Abf,
                                             float* __restrict__ psum,
                                             float* __restrict__ pcnt) {
    __shared__ __align__(16) unsigned short As[256 * 64], Bs[256 * 64];
    __shared__ int toks[512];
    __shared__ float sred[8], cred[8];
    int g = blockIdx.x;
    int xcd = g & 7, q = g >> 3;
    int q3 = q / 3;
    int b = xcd + (q3 << 3);
    int t = q - q3 * 3;                 // 0:(0,0) 1:(0,1) 2:(1,1)
    int tm = (t == 2) ? 1 : 0;
    int tn = (t == 0) ? 0 : 1;
    bool diag = (t != 1);
    int tid = threadIdx.x, lane = tid & 63, w = tid >> 6;
    if (tid < 256) toks[tid] = recd[b * 512 + tm * 256 + tid];
    else           toks[tid] = recd[b * 512 + tn * 256 + (tid - 256)];
    int wm = w >> 2, wn = w & 3;
    int fr = lane & 15, ko = (lane >> 4) * 8;
    __syncthreads();                    // publish toks
    // hoist this thread's staging tokens to registers (loop-invariant)
    int tokA[4], tokB[4];
#pragma unroll
    for (int i = 0; i < 4; ++i) {
        int r = (i * 512 + tid) >> 3;
        tokA[i] = toks[r];
        tokB[i] = toks[256 + r];
    }
    f32x4 acc[8][4] = {};
    for (int k0 = 0; k0 < 512; k0 += 64) {
        __syncthreads();
#pragma unroll
        for (int i = 0; i < 4; ++i) {
            int c = ((i * 512 + tid) & 7) * 8;
            gll16(rtb + (long)tokA[i] * 512 + k0 + c, As + (i * 64 + w * 8) * 64);
        }
        if (!diag) {
#pragma unroll
            for (int i = 0; i < 4; ++i) {
                int c = ((i * 512 + tid) & 7) * 8;
                gll16(rtb + (long)tokB[i] * 512 + k0 + c, Bs + (i * 64 + w * 8) * 64);
            }
        }
        __syncthreads();
        const unsigned short* Bsrc = diag ? As : Bs;
#pragma unroll
        for (int ks = 0; ks < 2; ++ks) {
            short8 a[8], bb[4];
#pragma unroll
            for (int m = 0; m < 8; ++m)
                a[m] = *(const short8*)(As + (wm * 128 + m * 16 + fr) * 64 + ks * 32 + ko);
#pragma unroll
            for (int n = 0; n < 4; ++n)
                bb[n] = *(const short8*)(Bsrc + (wn * 64 + n * 16 + fr) * 64 + ks * 32 + ko);
            __builtin_amdgcn_s_setprio(1);
#pragma unroll
            for (int m = 0; m < 8; ++m)
#pragma unroll
                for (int n = 0; n < 4; ++n)
                    acc[m][n] = __builtin_amdgcn_mfma_f32_16x16x32_bf16(
                        a[m], bb[n], acc[m][n], 0, 0, 0);
            __builtin_amdgcn_s_setprio(0);
        }
    }
    float s = 0.f, c = 0.f;
    unsigned short* Ab = Abf + (long)b * NN2;
    const float* rnb = rnorm + (long)b * 512;
#pragma unroll
    for (int m = 0; m < 8; ++m) {
        int gi0 = tm * 256 + wm * 128 + m * 16 + (lane >> 4) * 4;
        float4 rni = *(const float4*)(rnb + gi0);
#pragma unroll
        for (int n = 0; n < 4; ++n) {
            int gj = tn * 256 + wn * 64 + n * 16 + fr;
            float rj = rnb[gj];
            f32x4 v = acc[m][n];
            bf16x4 tw;
#pragma unroll
            for (int qq = 0; qq < 4; ++qq) {
                int gi = gi0 + qq;
                float vv = v[qq] * (&rni.x)[qq] * rj;
                unsigned short bv = f2bf(vv);
                Ab[(long)gi * N_ + gj] = bv;
                tw[qq] = bv;
                if (gj > gi) {
                    s += vv;
                    c += (vv != 0.0f) ? 1.0f : 0.0f;
                }
            }
            if (!diag)   // mirror: A[gj][gi0..gi0+3]
                *(bf16x4*)(Ab + (long)gj * N_ + gi0) = tw;
        }
    }
    s = wred(s);
    c = wred(c);
    if (lane == 0) { sred[w] = s; cred[w] = c; }
    __syncthreads();
    if (tid == 0) {
        float ss = 0.f, cc = 0.f;
#pragma unroll
        for (int i = 0; i < 8; ++i) { ss += sred[i]; cc += cred[i]; }
        psum[b * 16 + t] = ss;
        pcnt[b * 16 + t] = cc;
    }
}

// ---------------- fused: mean + mask + dinv + scale-transpose (XCD batch-affine) ----------------
__global__ __launch_bounds__(256) void k_degtrs(unsigned short* __restrict__ Abf,
                                                const float* __restrict__ psum,
                                                const float* __restrict__ pcnt,
                                                const unsigned short* __restrict__ xin,
                                                float* __restrict__ dinv,
                                                unsigned short* __restrict__ pT) {
    __shared__ unsigned char mb[4][64];
    __shared__ float sdinv[64];
    __shared__ unsigned short t[64 * 128];
    int bid = blockIdx.x;
    int q = bid >> 3, r8 = bid & 7;
    int b = r8 + ((q >> 3) << 3);       // same XCD as the k_adj blocks that wrote A[b]
    int tn = q & 7;
    int tid = threadIdx.x, lane = tid & 63, w = tid >> 6;
    float s = 0.f, c = 0.f;
#pragma unroll
    for (int k = 0; k < 3; ++k) { s += psum[b * 16 + k]; c += pcnt[b * 16 + k]; }
    float m = s / fmaxf(c, 1.0f);
#pragma unroll 1
    for (int i = 0; i < 16; ++i) {
        int rl = w * 16 + i;
        long r = (long)b * 512 + tn * 64 + rl;
        int ig = tn * 64 + rl;               // diagonal column for this row
        ushort8 v = *(const ushort8*)(Abf + r * 512 + lane * 8);
        unsigned byt = 0;
        int cnt = 0;
#pragma unroll
        for (int k = 0; k < 8; ++k) {
            float f = bf2f(v[k]);
            int j = lane * 8 + k;
            bool keep = (f >= m) && (f != 0.0f) && (j != ig);
            byt |= (keep ? 1u : 0u) << k;
            cnt += keep ? 1 : 0;
        }
        mb[w][lane] = (unsigned char)byt;
        float fc = wred((float)cnt);
        if (lane < 8) {
            unsigned long long mword = *(const unsigned long long*)&mb[w][lane * 8];
            *(unsigned long long*)((unsigned char*)Abf + r * 1024 + lane * 8) = mword;
        }
        if (lane == 8) {
            float dv = (fc > 0.f) ? rsqrtf(fc) : 0.f;
            dinv[r] = dv;
            sdinv[rl] = dv;
        }
    }
    __syncthreads();
    // phase C: scale-transpose x tile [64n x 128d] -> pT[b][d][tn*64+n]
    const unsigned short* ib = xin + ((long)b * 512 + tn * 64) * 128;
    unsigned short* ob = pT + (long)b * 65536 + tn * 64;
#pragma unroll
    for (int i = 0; i < 4; ++i) {
        int u = i * 256 + tid;          // 1024 ushort8 units
        int n = u >> 4, g = u & 15;
        float sc = sdinv[n];
        ushort8 v = *(const ushort8*)(ib + n * 128 + g * 8);
        ushort8 sv;
#pragma unroll
        for (int tt = 0; tt < 8; ++tt) sv[tt] = f2bf(bf2f(v[tt]) * sc);
        int gs = g ^ ((n >> 3) & 7);
        *(ushort8*)(t + n * 128 + gs * 8) = sv;
    }
    __syncthreads();
#pragma unroll
    for (int i = 0; i < 4; ++i) {
        int u = i * 256 + tid;
        int d = u >> 3, n8 = (u & 7) * 8;
        ushort8 v;
#pragma unroll
        for (int tt = 0; tt < 8; ++tt) {
            int n = n8 + tt;
            int g = (d >> 3) ^ ((n >> 3) & 7);
            v[tt] = t[n * 128 + g * 8 + (d & 7)];
        }
        *(ushort8*)(ob + (long)d * 512 + n8) = v;
    }
}

// ---------------- masked S-GEMM, full-panel-in-LDS, barrier-free K-loop ----------------
// 512 threads = 8 waves (4M x 2N); block = (batch b, half) -> 256 output rows.
__global__ __launch_bounds__(512) void k_sxm(const unsigned short* __restrict__ Abf,
                                             const float* __restrict__ dinv,
                                             const unsigned short* __restrict__ pT,
                                             unsigned short* __restrict__ outN,
                                             unsigned short* __restrict__ outT) {
    __shared__ __align__(16) unsigned short Ps[128 * PSTR];
    __shared__ __align__(8) unsigned short lut4[16 * 4];
    int tid = threadIdx.x, lane = tid & 63, w = tid >> 6;
    if (tid < 16) {   // nibble -> 4 bf16 {0,1}
        unsigned long long e = 0;
#pragma unroll
        for (int j = 0; j < 4; ++j)
            if ((tid >> j) & 1) e |= 0x3F80ull << (16 * j);
        *(unsigned long long*)(lut4 + tid * 4) = e;
    }
    int g = blockIdx.x;
    int xcd = g & 7, idx = g >> 3;          // idx 0..31
    int b = xcd + ((idx >> 1) << 3);        // XCD-affine batch
    int half = idx & 1;
    int wm = w >> 1, wn = w & 1;
    int fr = lane & 15, ko = (lane >> 4) * 8;
    const unsigned char* mbase = (const unsigned char*)Abf + (long)b * 524288;
    const unsigned short* pb = pT + (long)b * 65536;
#pragma unroll
    for (int i = 0; i < 16; ++i) {
        int r = i * 8 + w;
        gll16(pb + (long)r * 512 + lane * 8, Ps + r * PSTR);
    }
    __syncthreads();
    f32x4 acc[4][4] = {};
    int rowbase = half * 256 + wm * 64;
#pragma unroll 1
    for (int k0 = 0; k0 < 512; k0 += 128) {
        u64x2 mw[4];
#pragma unroll
        for (int m = 0; m < 4; ++m) {
            int row = rowbase + m * 16 + fr;
            mw[m] = *(const u64x2*)(mbase + (long)row * 1024 + (k0 >> 3));
        }
#pragma unroll
        for (int kss = 0; kss < 4; ++kss) {
            short8 a4[4], b4[4];
#pragma unroll
            for (int m = 0; m < 4; ++m) {
                unsigned w32 = (unsigned)(mw[m][kss >> 1] >> ((kss & 1) * 32));
                unsigned byt = (w32 >> ko) & 255u;
                unsigned long long lo = *(const unsigned long long*)(lut4 + (byt & 15u) * 4);
                unsigned long long hi = *(const unsigned long long*)(lut4 + (byt >> 4) * 4);
                u64x2 tt; tt[0] = lo; tt[1] = hi;
                a4[m] = __builtin_bit_cast(short8, tt);
            }
#pragma unroll
            for (int n = 0; n < 4; ++n)
                b4[n] = *(const short8*)(Ps + (wn * 64 + n * 16 + fr) * PSTR + k0 + kss * 32 + ko);
            __builtin_amdgcn_s_setprio(1);
#pragma unroll
            for (int m = 0; m < 4; ++m)
#pragma unroll
                for (int n = 0; n < 4; ++n)
                    acc[m][n] = __builtin_amdgcn_mfma_f32_16x16x32_bf16(
                        a4[m], b4[n], acc[m][n], 0, 0, 0);
            __builtin_amdgcn_s_setprio(0);
        }
    }
    unsigned short* on = outN + (long)b * 65536;
#pragma unroll
    for (int m = 0; m < 4; ++m) {
        int gi0 = half * 256 + wm * 64 + m * 16 + ((lane >> 4) << 2);
        float4 dv = *(const float4*)(dinv + (long)b * 512 + gi0);
#pragma unroll
        for (int n = 0; n < 4; ++n) {
            int gj = wn * 64 + n * 16 + fr;
            bf16x4 tw;
#pragma unroll
            for (int qq = 0; qq < 4; ++qq) {
                float dq = (&dv.x)[qq];
                float t1v = -dq * acc[m][n][qq];
                on[(long)(gi0 + qq) * 128 + gj] = f2bf(t1v);
                tw[qq] = f2bf(dq * t1v);
            }
            *(bf16x4*)(outT + (long)b * 65536 + (long)gj * 512 + gi0) = tw;
        }
    }
}

// ---------------- fused: u = S t1 (full-panel phase) + 3-term projection (staged) ----------------
// 512 threads, block = (b, half) -> 256 rows. LDS: phase1 panel 128x520;
// phase2 reuses it as As[256x64] | Bs[128x64] | uLds[256][136].
template <int LAYER>
__global__ __launch_bounds__(512) void k_sxp(const unsigned short* __restrict__ Abf,
                                             const float* __restrict__ dinv,
                                             const unsigned short* __restrict__ pTin,
                                             const unsigned short* __restrict__ t0,
                                             const unsigned short* __restrict__ t1,
                                             const unsigned short* __restrict__ wTl,
                                             const float* __restrict__ bias,
                                             unsigned short* __restrict__ ybf,
                                             unsigned short* __restrict__ pTout,
                                             float* __restrict__ out) {
    __shared__ __align__(16) unsigned short lds[128 * PSTR];   // 133,120 B
    __shared__ __align__(8) unsigned short lut4[16 * 4];
    int tid = threadIdx.x, lane = tid & 63, w = tid >> 6;
    if (tid < 16) {
        unsigned long long e = 0;
#pragma unroll
        for (int j = 0; j < 4; ++j)
            if ((tid >> j) & 1) e |= 0x3F80ull << (16 * j);
        *(unsigned long long*)(lut4 + tid * 4) = e;
    }
    int g = blockIdx.x;
    int xcd = g & 7, idx = g >> 3;
    int b = xcd + ((idx >> 1) << 3);
    int half = idx & 1;
    int wm = w >> 1, wn = w & 1;
    int fr = lane & 15, ko = (lane >> 4) * 8;
    unsigned short* As  = lds;            // 256x64 (16384 ushorts)
    unsigned short* Bs  = lds + 16384;    // 128x64 (8192)
    unsigned short* uL  = lds + 24576;    // 256x136 (34816)
    // ---- phase 1: u rows [half*256,+256) = A_bin @ pTin, panel in LDS ----
    {
        const unsigned char* mbase = (const unsigned char*)Abf + (long)b * 524288;
        const unsigned short* pb = pTin + (long)b * 65536;
#pragma unroll
        for (int i = 0; i < 16; ++i) {
            int r = i * 8 + w;
            gll16(pb + (long)r * 512 + lane * 8, lds + r * PSTR);
        }
        __syncthreads();
        f32x4 acc[4][4] = {};
        int rowbase = half * 256 + wm * 64;
#pragma unroll 1
        for (int k0 = 0; k0 < 512; k0 += 128) {
            u64x2 mw[4];
#pragma unroll
            for (int m = 0; m < 4; ++m) {
                int row = rowbase + m * 16 + fr;
                mw[m] = *(const u64x2*)(mbase + (long)row * 1024 + (k0 >> 3));
            }
#pragma unroll
            for (int kss = 0; kss < 4; ++kss) {
                short8 a4[4], b4[4];
#pragma unroll
                for (int m = 0; m < 4; ++m) {
                    unsigned w32 = (unsigned)(mw[m][kss >> 1] >> ((kss & 1) * 32));
                    unsigned byt = (w32 >> ko) & 255u;
                    unsigned long long lo = *(const unsigned long long*)(lut4 + (byt & 15u) * 4);
                    unsigned long long hi = *(const unsigned long long*)(lut4 + (byt >> 4) * 4);
                    u64x2 tt; tt[0] = lo; tt[1] = hi;
                    a4[m] = __builtin_bit_cast(short8, tt);
                }
#pragma unroll
                for (int n = 0; n < 4; ++n)
                    b4[n] = *(const short8*)(lds + (wn * 64 + n * 16 + fr) * PSTR + k0 + kss * 32 + ko);
                __builtin_amdgcn_s_setprio(1);
#pragma unroll
                for (int m = 0; m < 4; ++m)
#pragma unroll
                    for (int n = 0; n < 4; ++n)
                        acc[m][n] = __builtin_amdgcn_mfma_f32_16x16x32_bf16(
                            a4[m], b4[n], acc[m][n], 0, 0, 0);
                __builtin_amdgcn_s_setprio(0);
            }
        }
        __syncthreads();    // all panel reads done before uL overwrites it
        // park u = bf16(-dinv*acc) in uLds [256][136]
#pragma unroll
        for (int m = 0; m < 4; ++m) {
            int li0 = wm * 64 + m * 16 + ((lane >> 4) << 2);   // 0..255
            float4 dv = *(const float4*)(dinv + (long)b * 512 + half * 256 + li0);
#pragma unroll
            for (int n = 0; n < 4; ++n) {
                int gj = wn * 64 + n * 16 + fr;
#pragma unroll
                for (int qq = 0; qq < 4; ++qq)
                    uL[(li0 + qq) * USTR + gj] = f2bf(-(&dv.x)[qq] * acc[m][n][qq]);
            }
        }
    }
    // ---- phase 2: y = relu(t0 m0 + t1 m1 + u m2 + bias) over 256 rows ----
    long row0 = (long)b * 512 + half * 256;
    f32x4 acc2[4][4] = {};
#pragma unroll 1
    for (int mat = 0; mat < 2; ++mat) {
        const unsigned short* tsrc = (mat == 0) ? (t0 + row0 * D_) : (t1 + row0 * D_);
        const unsigned short* wsrc = wTl + mat * 16384;
#pragma unroll 1
        for (int k0 = 0; k0 < 128; k0 += 64) {
            __syncthreads();
            stageA256(tsrc, k0, As, tid);
            stageB128(wsrc, k0, Bs, tid);
            __syncthreads();
#pragma unroll
            for (int ks = 0; ks < 2; ++ks) {
                short8 a[4], bfr[4];
#pragma unroll
                for (int m = 0; m < 4; ++m)
                    a[m] = *(const short8*)(As + (wm * 64 + m * 16 + fr) * 64 + ks * 32 + ko);
#pragma unroll
                for (int n = 0; n < 4; ++n)
                    bfr[n] = *(const short8*)(Bs + (wn * 64 + n * 16 + fr) * 64 + ks * 32 + ko);
#pragma unroll
                for (int m = 0; m < 4; ++m)
#pragma unroll
                    for (int n = 0; n < 4; ++n)
                        acc2[m][n] = __builtin_amdgcn_mfma_f32_16x16x32_bf16(
                            a[m], bfr[n], acc2[m][n], 0, 0, 0);
            }
        }
    }
    // u-term: A-frags from uLds
#pragma unroll 1
    for (int s2 = 0; s2 < 2; ++s2) {
        __syncthreads();
        stageB128(wTl + 32768, s2 * 64, Bs, tid);
        __syncthreads();
#pragma unroll
        for (int ks = 0; ks < 2; ++ks) {
            short8 a[4], bfr[4];
#pragma unroll
            for (int m = 0; m < 4; ++m)
                a[m] = *(const short8*)(uL + (wm * 64 + m * 16 + fr) * USTR + s2 * 64 + ks * 32 + ko);
#pragma unroll
            for (int n = 0; n < 4; ++n)
                bfr[n] = *(const short8*)(Bs + (wn * 64 + n * 16 + fr) * 64 + ks * 32 + ko);
#pragma unroll
            for (int m = 0; m < 4; ++m)
#pragma unroll
                for (int n = 0; n < 4; ++n)
                    acc2[m][n] = __builtin_amdgcn_mfma_f32_16x16x32_bf16(
                        a[m], bfr[n], acc2[m][n], 0, 0, 0);
        }
    }
    // ---- epilogue ----
#pragma unroll
    for (int m = 0; m < 4; ++m) {
        long gr0 = row0 + wm * 64 + m * 16 + ((lane >> 4) << 2);
        float4 dv;
        if (LAYER == 1) dv = *(const float4*)(dinv + gr0);
#pragma unroll
        for (int n = 0; n < 4; ++n) {
            int gj = wn * 64 + n * 16 + (lane & 15);
            bf16x4 tw;
#pragma unroll
            for (int qq = 0; qq < 4; ++qq) {
                long gr = gr0 + qq;
                float v = fmaxf(acc2[m][n][qq] + bias[gj], 0.0f);
                if (LAYER == 1) {
                    ybf[gr * D_ + gj] = f2bf(v);
                    tw[qq] = f2bf((&dv.x)[qq] * v);
                } else {
                    out[gr * 640 + gj] = v;
                }
            }
            if (LAYER == 1)
                *(bf16x4*)(pTout + (gr0 >> 9) * 65536 + (long)gj * 512 + (gr0 & 511)) = tw;
        }
    }
}

// ---------------- host ----------------

extern "C" void kernel_launch(void* const* d_in, const int* in_sizes, int n_in,
                              void* d_out, int out_size, void* d_ws, size_t ws_size,
                              hipStream_t stream) {
    const int* seq    = (const int*)d_in[0];
    const int* recd   = (const int*)d_in[1];
    const float* etab = (const float*)d_in[2];
    const float* rtab = (const float*)d_in[3];
    const float* w1   = (const float*)d_in[4];
    const float* b1   = (const float*)d_in[5];
    const float* w2   = (const float*)d_in[6];
    const float* b2   = (const float*)d_in[7];
    float* out = (float*)d_out;
    char* ws = (char*)d_ws;

    if (ws_size < 151470592u) return;

    unsigned short* Abf  = (unsigned short*)(ws);
    unsigned short* pTa  = (unsigned short*)(ws + 67108864);
    unsigned short* pTb  = (unsigned short*)(ws + 83886080);
    unsigned short* t1   = (unsigned short*)(ws + 100663296);
    unsigned short* rtb  = (unsigned short*)(ws + 117440512);   // 5,120,000 B
    float* rnorm         = (float*)(ws + 122683392);            // 262,144 B
    unsigned short* xbf  = (unsigned short*)(ws + 134217728);
    unsigned short* wT   = (unsigned short*)(ws + 150994944);
    float* psum = (float*)(ws + 151191552);
    float* pcnt = (float*)(ws + 151199744);
    float* dinv = (float*)(ws + 151208448);

    k_front<<<22114, 256, 0, stream>>>(recd, rtab, seq, etab, w1, w2,
                                       out, xbf, wT, rtb, rnorm);
    k_adj<<<384, 512, 0, stream>>>(rtb, recd, rnorm, Abf, psum, pcnt);
    k_degtrs<<<1024, 256, 0, stream>>>(Abf, psum, pcnt, xbf, dinv, pTa);
    // layer 1
    k_sxm<<<256, 512, 0, stream>>>(Abf, dinv, pTa, t1, pTb);                    // t1 = Sx, pTb
    k_sxp<1><<<256, 512, 0, stream>>>(Abf, dinv, pTb, xbf, t1, wT, b1,
                                      xbf, pTa, nullptr);                       // y->xbf, pTa
    // layer 2
    k_sxm<<<256, 512, 0, stream>>>(Abf, dinv, pTa, t1, pTb);
    k_sxp<2><<<256, 512, 0, stream>>>(Abf, dinv, pTb, xbf, t1, wT + 49152, b2,
                                      nullptr, nullptr, out);
}

// Round 15
// 220.620 us; speedup vs baseline: 1.0783x; 1.0783x over previous
//
#include <hip/hip_runtime.h>
#include <hip/hip_bf16.h>

typedef __attribute__((ext_vector_type(8))) unsigned short ushort8;
typedef __attribute__((ext_vector_type(4))) unsigned short bf16x4;
typedef __attribute__((ext_vector_type(8))) short short8;
typedef __attribute__((ext_vector_type(4))) float f32x4;
typedef __attribute__((ext_vector_type(2))) unsigned long long u64x2;

#define DEV __device__ __forceinline__

DEV unsigned short f2bf(float f) {
    unsigned u = __builtin_bit_cast(unsigned, f);
    return (unsigned short)((u + 0x7fffu + ((u >> 16) & 1u)) >> 16);
}
DEV float bf2f(unsigned short h) {
    unsigned u = ((unsigned)h) << 16;
    return __builtin_bit_cast(float, u);
}
DEV float wred(float v) {
#pragma unroll
    for (int m = 32; m > 0; m >>= 1) v += __shfl_xor(v, m, 64);
    return v;
}

constexpr int N_ = 512, D_ = 128, R_ = 512;
constexpr long NN2 = (long)N_ * N_;          // 262144
constexpr int PSTR = 520;                    // padded panel row stride (ushorts)
constexpr int USTR = 136;                    // padded uLds row stride

// async global->LDS, 16B per lane. LDS dest = wave-uniform base + lane*16.
// GLOBAL source is per-lane -> gather-staging works.
DEV void gll16(const void* g, void* l) {
    __builtin_amdgcn_global_load_lds(
        (const __attribute__((address_space(1))) unsigned*)g,
        (__attribute__((address_space(3))) unsigned*)l, 16, 0, 0);
}

// ---------------- fused front: gather_app | gather_x | wT | rtab->bf16 ----------------

__global__ __launch_bounds__(256) void k_front(const int* __restrict__ recd,
                                               const float* __restrict__ rtab,
                                               const int* __restrict__ seq,
                                               const float* __restrict__ etab,
                                               const float* __restrict__ w1,
                                               const float* __restrict__ w2,
                                               float* __restrict__ out,
                                               unsigned short* __restrict__ x,
                                               unsigned short* __restrict__ wT,
                                               unsigned short* __restrict__ rtb,
                                               float* __restrict__ rnorm) {
    int bid = blockIdx.x, tid = threadIdx.x;
    if (bid < 16384) {                       // ---- gather_app: out cols 128..639 + rnorm ----
        int lane = tid & 63, w = tid >> 6;
        long r = (long)bid * 4 + w;
        int tok = recd[r];
        const float* src = rtab + (long)tok * R_;
        int j = lane * 8;
        float4 v0 = *(const float4*)(src + j);
        float4 v1 = *(const float4*)(src + j + 4);
        float ssq = v0.x*v0.x + v0.y*v0.y + v0.z*v0.z + v0.w*v0.w
                  + v1.x*v1.x + v1.y*v1.y + v1.z*v1.z + v1.w*v1.w;
        ssq = wred(ssq);
        float* o = out + r * 640 + 128 + j;
        *(float4*)o = v0;
        *(float4*)(o + 4) = v1;
        if (lane == 0) rnorm[r] = 1.0f / fmaxf(sqrtf(ssq), 1e-12f);
    } else if (bid < 20480) {                // ---- gather_x ----
        long e8 = ((long)(bid - 16384) * 256 + tid) * 8;
        long r = e8 >> 7;
        int d0 = (int)(e8 & 127);
        int tok = seq[r];
        const float* src = etab + (long)tok * D_ + d0;
        float4 v0 = *(const float4*)src, v1 = *(const float4*)(src + 4);
        ushort8 u;
        u[0]=f2bf(v0.x); u[1]=f2bf(v0.y); u[2]=f2bf(v0.z); u[3]=f2bf(v0.w);
        u[4]=f2bf(v1.x); u[5]=f2bf(v1.y); u[6]=f2bf(v1.z); u[7]=f2bf(v1.w);
        *(ushort8*)(x + e8) = u;
    } else if (bid < 20864) {                // ---- wT (folded weights) ----
        int o = (bid - 20480) * 256 + tid;   // < 98304
        int l = o / 49152;
        int rr = o - l * 49152;
        int mat = rr >> 14;
        int e2 = rr & 16383;
        int e = e2 >> 7, d = e2 & 127;
        const float* w = l ? w2 : w1;
        float v;
        if (mat == 0)      v = w[d * 128 + e] - w[32768 + d * 128 + e];
        else if (mat == 1) v = w[16384 + d * 128 + e];
        else               v = 2.0f * w[32768 + d * 128 + e];
        wT[o] = f2bf(v);
    } else {                                 // ---- rtab -> bf16 copy (5000x512) ----
        long e8 = ((long)(bid - 20864) * 256 + tid) * 8;   // < 2,560,000
        float4 v0 = *(const float4*)(rtab + e8), v1 = *(const float4*)(rtab + e8 + 4);
        ushort8 u;
        u[0]=f2bf(v0.x); u[1]=f2bf(v0.y); u[2]=f2bf(v0.z); u[3]=f2bf(v0.w);
        u[4]=f2bf(v1.x); u[5]=f2bf(v1.y); u[6]=f2bf(v1.z); u[7]=f2bf(v1.w);
        *(ushort8*)(rtb + e8) = u;
    }
}

// ---------------- staging helpers (256-thread blocks) ----------------

DEV void stage_rowmajor(const unsigned short* base, long ld, int k0,
                        unsigned short* dst, int tid) {
#pragma unroll
    for (int i = 0; i < 4; ++i) {
        int u = i * 256 + tid;        // 0..1023 16B units (128 rows x 64)
        int r = u >> 3, c = (u & 7) * 8;
        gll16(base + (long)r * ld + k0 + c,
              dst + i * 2048 + (tid & 448) * 8);
    }
}

// gather-stage 128 rows x 64 cols from token-indexed table rows
DEV void stage_gather(const unsigned short* tab, const int* toks, int k0,
                      unsigned short* dst, int tid) {
#pragma unroll
    for (int i = 0; i < 4; ++i) {
        int u = i * 256 + tid;
        int r = u >> 3, c = (u & 7) * 8;
        gll16(tab + (long)toks[r] * 512 + k0 + c,
              dst + i * 2048 + (tid & 448) * 8);
    }
}

// ---------------- staging helpers (512-thread blocks) ----------------

// 256 rows x 64 cols, ld=128, dst rowstride 64
DEV void stageA256(const unsigned short* base, int k0, unsigned short* dst, int tid) {
    int w = tid >> 6;
#pragma unroll
    for (int i = 0; i < 4; ++i) {
        int u = i * 512 + tid;
        int r = u >> 3, c = (u & 7) * 8;
        gll16(base + (long)r * 128 + k0 + c, dst + (i * 64 + w * 8) * 64);
    }
}

// 128 rows x 64 cols, ld=128, dst rowstride 64
DEV void stageB128(const unsigned short* base, int k0, unsigned short* dst, int tid) {
    int w = tid >> 6;
#pragma unroll
    for (int i = 0; i < 2; ++i) {
        int u = i * 512 + tid;
        int r = u >> 3, c = (u & 7) * 8;
        gll16(base + (long)r * 128 + k0 + c, dst + (i * 64 + w * 8) * 64);
    }
}

// ---------------- adjacency: gather-staged panels (A and B), epilogue-normalized ----------------
// A_ij = dot(raw_i, raw_j) * rn_i * rn_j

__global__ __launch_bounds__(256) void k_adj(const unsigned short* __restrict__ rtb,
                                             const int* __restrict__ recd,
                                             const float* __restrict__ rnorm,
                                             unsigned short* __restrict__ Abf,
                                             float* __restrict__ psum,
                                             float* __restrict__ pcnt) {
    __shared__ __align__(16) unsigned short As[128 * 64], Bs[128 * 64];
    __shared__ int toks[256];
    __shared__ float sred[4], cred[4];
    int g = blockIdx.x;
    int r8 = g & 7, q = g >> 3;
    int q10 = q / 10;
    int b = r8 + (q10 << 3);
    int t = q - q10 * 10;               // 0..9 upper-triangle tile id
    int tm = (t < 4) ? 0 : (t < 7) ? 1 : (t < 9) ? 2 : 3;
    int tn = t - (tm * (9 - tm)) / 2 + tm;
    bool diag = (tm == tn);
    int tid = threadIdx.x, lane = tid & 63, wave = tid >> 6;
    if (tid < 128) toks[tid] = recd[b * 512 + tm * 128 + tid];
    else           toks[tid] = recd[b * 512 + tn * 128 + (tid - 128)];
    int wm = wave >> 1, wn = wave & 1;
    int fr = lane & 15, ko = (lane >> 4) * 8;
    f32x4 acc[4][4] = {};
    for (int k0 = 0; k0 < 512; k0 += 64) {
        __syncthreads();                      // first iter also publishes toks
        stage_gather(rtb, toks, k0, As, tid);
        if (!diag) stage_gather(rtb, toks + 128, k0, Bs, tid);
        __syncthreads();
        const unsigned short* Bsrc = diag ? As : Bs;
#pragma unroll
        for (int ks = 0; ks < 2; ++ks) {
            short8 a[4], bb[4];
#pragma unroll
            for (int m = 0; m < 4; ++m)
                a[m] = *(const short8*)(As + (wm * 64 + m * 16 + fr) * 64 + ks * 32 + ko);
#pragma unroll
            for (int n = 0; n < 4; ++n)
                bb[n] = *(const short8*)(Bsrc + (wn * 64 + n * 16 + fr) * 64 + ks * 32 + ko);
#pragma unroll
            for (int m = 0; m < 4; ++m)
#pragma unroll
                for (int n = 0; n < 4; ++n)
                    acc[m][n] = __builtin_amdgcn_mfma_f32_16x16x32_bf16(
                        a[m], bb[n], acc[m][n], 0, 0, 0);
        }
    }
    float s = 0.f, c = 0.f;
    unsigned short* Ab = Abf + (long)b * NN2;
    const float* rnb = rnorm + (long)b * 512;
#pragma unroll
    for (int m = 0; m < 4; ++m) {
        int gi0 = tm * 128 + wm * 64 + m * 16 + (lane >> 4) * 4;
        float4 rni = *(const float4*)(rnb + gi0);
#pragma unroll
        for (int n = 0; n < 4; ++n) {
            int gj = tn * 128 + wn * 64 + n * 16 + fr;
            float rj = rnb[gj];
            f32x4 v = acc[m][n];
            bf16x4 tw;
#pragma unroll
            for (int qq = 0; qq < 4; ++qq) {
                int gi = gi0 + qq;
                float vv = v[qq] * (&rni.x)[qq] * rj;
                unsigned short bv = f2bf(vv);
                Ab[(long)gi * N_ + gj] = bv;
                tw[qq] = bv;
                if (gj > gi) {
                    s += vv;
                    c += (vv != 0.0f) ? 1.0f : 0.0f;
                }
            }
            if (!diag)   // mirror: A[gj][gi0..gi0+3]
                *(bf16x4*)(Ab + (long)gj * N_ + gi0) = tw;
        }
    }
    s = wred(s);
    c = wred(c);
    if (lane == 0) { sred[wave] = s; cred[wave] = c; }
    __syncthreads();
    if (tid == 0) {
        psum[b * 16 + t] = sred[0] + sred[1] + sred[2] + sred[3];
        pcnt[b * 16 + t] = cred[0] + cred[1] + cred[2] + cred[3];
    }
}

// ---------------- fused: mean + mask + dinv + scale-transpose (XCD batch-affine) ----------------
__global__ __launch_bounds__(256) void k_degtrs(unsigned short* __restrict__ Abf,
                                                const float* __restrict__ psum,
                                                const float* __restrict__ pcnt,
                                                const unsigned short* __restrict__ xin,
                                                float* __restrict__ dinv,
                                                unsigned short* __restrict__ pT) {
    __shared__ unsigned char mb[4][64];
    __shared__ float sdinv[64];
    __shared__ unsigned short t[64 * 128];
    int bid = blockIdx.x;
    int q = bid >> 3, r8 = bid & 7;
    int b = r8 + ((q >> 3) << 3);       // same XCD as the k_adj blocks that wrote A[b]
    int tn = q & 7;
    int tid = threadIdx.x, lane = tid & 63, w = tid >> 6;
    float s = 0.f, c = 0.f;
#pragma unroll
    for (int k = 0; k < 10; ++k) { s += psum[b * 16 + k]; c += pcnt[b * 16 + k]; }
    float m = s / fmaxf(c, 1.0f);
#pragma unroll 1
    for (int i = 0; i < 16; ++i) {
        int rl = w * 16 + i;
        long r = (long)b * 512 + tn * 64 + rl;
        int ig = tn * 64 + rl;               // diagonal column for this row
        ushort8 v = *(const ushort8*)(Abf + r * 512 + lane * 8);
        unsigned byt = 0;
        int cnt = 0;
#pragma unroll
        for (int k = 0; k < 8; ++k) {
            float f = bf2f(v[k]);
            int j = lane * 8 + k;
            bool keep = (f >= m) && (f != 0.0f) && (j != ig);
            byt |= (keep ? 1u : 0u) << k;
            cnt += keep ? 1 : 0;
        }
        mb[w][lane] = (unsigned char)byt;
        float fc = wred((float)cnt);
        if (lane < 8) {
            unsigned long long mword = *(const unsigned long long*)&mb[w][lane * 8];
            *(unsigned long long*)((unsigned char*)Abf + r * 1024 + lane * 8) = mword;
        }
        if (lane == 8) {
            float dv = (fc > 0.f) ? rsqrtf(fc) : 0.f;
            dinv[r] = dv;
            sdinv[rl] = dv;
        }
    }
    __syncthreads();
    // phase C: scale-transpose x tile [64n x 128d] -> pT[b][d][tn*64+n]
    const unsigned short* ib = xin + ((long)b * 512 + tn * 64) * 128;
    unsigned short* ob = pT + (long)b * 65536 + tn * 64;
#pragma unroll
    for (int i = 0; i < 4; ++i) {
        int u = i * 256 + tid;          // 1024 ushort8 units
        int n = u >> 4, g = u & 15;
        float sc = sdinv[n];
        ushort8 v = *(const ushort8*)(ib + n * 128 + g * 8);
        ushort8 sv;
#pragma unroll
        for (int tt = 0; tt < 8; ++tt) sv[tt] = f2bf(bf2f(v[tt]) * sc);
        int gs = g ^ ((n >> 3) & 7);
        *(ushort8*)(t + n * 128 + gs * 8) = sv;
    }
    __syncthreads();
#pragma unroll
    for (int i = 0; i < 4; ++i) {
        int u = i * 256 + tid;
        int d = u >> 3, n8 = (u & 7) * 8;
        ushort8 v;
#pragma unroll
        for (int tt = 0; tt < 8; ++tt) {
            int n = n8 + tt;
            int g = (d >> 3) ^ ((n >> 3) & 7);
            v[tt] = t[n * 128 + g * 8 + (d & 7)];
        }
        *(ushort8*)(ob + (long)d * 512 + n8) = v;
    }
}

// ---------------- masked S-GEMM, full-panel-in-LDS, barrier-free K-loop ----------------
// 512 threads = 8 waves (4M x 2N); block = (batch b, half) -> 256 output rows.
__global__ __launch_bounds__(512) void k_sxm(const unsigned short* __restrict__ Abf,
                                             const float* __restrict__ dinv,
                                             const unsigned short* __restrict__ pT,
                                             unsigned short* __restrict__ outN,
                                             unsigned short* __restrict__ outT) {
    __shared__ __align__(16) unsigned short Ps[128 * PSTR];
    __shared__ __align__(8) unsigned short lut4[16 * 4];
    int tid = threadIdx.x, lane = tid & 63, w = tid >> 6;
    if (tid < 16) {   // nibble -> 4 bf16 {0,1}
        unsigned long long e = 0;
#pragma unroll
        for (int j = 0; j < 4; ++j)
            if ((tid >> j) & 1) e |= 0x3F80ull << (16 * j);
        *(unsigned long long*)(lut4 + tid * 4) = e;
    }
    int g = blockIdx.x;
    int xcd = g & 7, idx = g >> 3;          // idx 0..31
    int b = xcd + ((idx >> 1) << 3);        // XCD-affine batch
    int half = idx & 1;
    int wm = w >> 1, wn = w & 1;
    int fr = lane & 15, ko = (lane >> 4) * 8;
    const unsigned char* mbase = (const unsigned char*)Abf + (long)b * 524288;
    const unsigned short* pb = pT + (long)b * 65536;
#pragma unroll
    for (int i = 0; i < 16; ++i) {
        int r = i * 8 + w;
        gll16(pb + (long)r * 512 + lane * 8, Ps + r * PSTR);
    }
    __syncthreads();
    f32x4 acc[4][4] = {};
    int rowbase = half * 256 + wm * 64;
#pragma unroll 1
    for (int k0 = 0; k0 < 512; k0 += 128) {
        u64x2 mw[4];
#pragma unroll
        for (int m = 0; m < 4; ++m) {
            int row = rowbase + m * 16 + fr;
            mw[m] = *(const u64x2*)(mbase + (long)row * 1024 + (k0 >> 3));
        }
#pragma unroll
        for (int kss = 0; kss < 4; ++kss) {
            short8 a4[4], b4[4];
#pragma unroll
            for (int m = 0; m < 4; ++m) {
                unsigned w32 = (unsigned)(mw[m][kss >> 1] >> ((kss & 1) * 32));
                unsigned byt = (w32 >> ko) & 255u;
                unsigned long long lo = *(const unsigned long long*)(lut4 + (byt & 15u) * 4);
                unsigned long long hi = *(const unsigned long long*)(lut4 + (byt >> 4) * 4);
                u64x2 tt; tt[0] = lo; tt[1] = hi;
                a4[m] = __builtin_bit_cast(short8, tt);
            }
#pragma unroll
            for (int n = 0; n < 4; ++n)
                b4[n] = *(const short8*)(Ps + (wn * 64 + n * 16 + fr) * PSTR + k0 + kss * 32 + ko);
            __builtin_amdgcn_s_setprio(1);
#pragma unroll
            for (int m = 0; m < 4; ++m)
#pragma unroll
                for (int n = 0; n < 4; ++n)
                    acc[m][n] = __builtin_amdgcn_mfma_f32_16x16x32_bf16(
                        a4[m], b4[n], acc[m][n], 0, 0, 0);
            __builtin_amdgcn_s_setprio(0);
        }
    }
    unsigned short* on = outN + (long)b * 65536;
#pragma unroll
    for (int m = 0; m < 4; ++m) {
        int gi0 = half * 256 + wm * 64 + m * 16 + ((lane >> 4) << 2);
        float4 dv = *(const float4*)(dinv + (long)b * 512 + gi0);
#pragma unroll
        for (int n = 0; n < 4; ++n) {
            int gj = wn * 64 + n * 16 + fr;
            bf16x4 tw;
#pragma unroll
            for (int qq = 0; qq < 4; ++qq) {
                float dq = (&dv.x)[qq];
                float t1v = -dq * acc[m][n][qq];
                on[(long)(gi0 + qq) * 128 + gj] = f2bf(t1v);
                tw[qq] = f2bf(dq * t1v);
            }
            *(bf16x4*)(outT + (long)b * 65536 + (long)gj * 512 + gi0) = tw;
        }
    }
}

// ---------------- fused: u = S t1 (full-panel phase) + 3-term projection (staged) ----------------
// 512 threads, block = (b, half) -> 256 rows. LDS: phase1 panel 128x520;
// phase2 reuses it as As[256x64] | Bs[128x64] | uLds[256][136].
template <int LAYER>
__global__ __launch_bounds__(512) void k_sxp(const unsigned short* __restrict__ Abf,
                                             const float* __restrict__ dinv,
                                             const unsigned short* __restrict__ pTin,
                                             const unsigned short* __restrict__ t0,
                                             const unsigned short* __restrict__ t1,
                                             const unsigned short* __restrict__ wTl,
                                             const float* __restrict__ bias,
                                             unsigned short* __restrict__ ybf,
                                             unsigned short* __restrict__ pTout,
                                             float* __restrict__ out) {
    __shared__ __align__(16) unsigned short lds[128 * PSTR];   // 133,120 B
    __shared__ __align__(8) unsigned short lut4[16 * 4];
    int tid = threadIdx.x, lane = tid & 63, w = tid >> 6;
    if (tid < 16) {
        unsigned long long e = 0;
#pragma unroll
        for (int j = 0; j < 4; ++j)
            if ((tid >> j) & 1) e |= 0x3F80ull << (16 * j);
        *(unsigned long long*)(lut4 + tid * 4) = e;
    }
    int g = blockIdx.x;
    int xcd = g & 7, idx = g >> 3;
    int b = xcd + ((idx >> 1) << 3);
    int half = idx & 1;
    int wm = w >> 1, wn = w & 1;
    int fr = lane & 15, ko = (lane >> 4) * 8;
    unsigned short* As  = lds;            // 256x64 (16384 ushorts)
    unsigned short* Bs  = lds + 16384;    // 128x64 (8192)
    unsigned short* uL  = lds + 24576;    // 256x136 (34816)
    // ---- phase 1: u rows [half*256,+256) = A_bin @ pTin, panel in LDS ----
    {
        const unsigned char* mbase = (const unsigned char*)Abf + (long)b * 524288;
        const unsigned short* pb = pTin + (long)b * 65536;
#pragma unroll
        for (int i = 0; i < 16; ++i) {
            int r = i * 8 + w;
            gll16(pb + (long)r * 512 + lane * 8, lds + r * PSTR);
        }
        __syncthreads();
        f32x4 acc[4][4] = {};
        int rowbase = half * 256 + wm * 64;
#pragma unroll 1
        for (int k0 = 0; k0 < 512; k0 += 128) {
            u64x2 mw[4];
#pragma unroll
            for (int m = 0; m < 4; ++m) {
                int row = rowbase + m * 16 + fr;
                mw[m] = *(const u64x2*)(mbase + (long)row * 1024 + (k0 >> 3));
            }
#pragma unroll
            for (int kss = 0; kss < 4; ++kss) {
                short8 a4[4], b4[4];
#pragma unroll
                for (int m = 0; m < 4; ++m) {
                    unsigned w32 = (unsigned)(mw[m][kss >> 1] >> ((kss & 1) * 32));
                    unsigned byt = (w32 >> ko) & 255u;
                    unsigned long long lo = *(const unsigned long long*)(lut4 + (byt & 15u) * 4);
                    unsigned long long hi = *(const unsigned long long*)(lut4 + (byt >> 4) * 4);
                    u64x2 tt; tt[0] = lo; tt[1] = hi;
                    a4[m] = __builtin_bit_cast(short8, tt);
                }
#pragma unroll
                for (int n = 0; n < 4; ++n)
                    b4[n] = *(const short8*)(lds + (wn * 64 + n * 16 + fr) * PSTR + k0 + kss * 32 + ko);
                __builtin_amdgcn_s_setprio(1);
#pragma unroll
                for (int m = 0; m < 4; ++m)
#pragma unroll
                    for (int n = 0; n < 4; ++n)
                        acc[m][n] = __builtin_amdgcn_mfma_f32_16x16x32_bf16(
                            a4[m], b4[n], acc[m][n], 0, 0, 0);
                __builtin_amdgcn_s_setprio(0);
            }
        }
        __syncthreads();    // all panel reads done before uL overwrites it
        // park u = bf16(-dinv*acc) in uLds [256][136]
#pragma unroll
        for (int m = 0; m < 4; ++m) {
            int li0 = wm * 64 + m * 16 + ((lane >> 4) << 2);   // 0..255
            float4 dv = *(const float4*)(dinv + (long)b * 512 + half * 256 + li0);
#pragma unroll
            for (int n = 0; n < 4; ++n) {
                int gj = wn * 64 + n * 16 + fr;
#pragma unroll
                for (int qq = 0; qq < 4; ++qq)
                    uL[(li0 + qq) * USTR + gj] = f2bf(-(&dv.x)[qq] * acc[m][n][qq]);
            }
        }
    }
    // ---- phase 2: y = relu(t0 m0 + t1 m1 + u m2 + bias) over 256 rows ----
    long row0 = (long)b * 512 + half * 256;
    f32x4 acc2[4][4] = {};
#pragma unroll 1
    for (int mat = 0; mat < 2; ++mat) {
        const unsigned short* tsrc = (mat == 0) ? (t0 + row0 * D_) : (t1 + row0 * D_);
        const unsigned short* wsrc = wTl + mat * 16384;
#pragma unroll 1
        for (int k0 = 0; k0 < 128; k0 += 64) {
            __syncthreads();
            stageA256(tsrc, k0, As, tid);
            stageB128(wsrc, k0, Bs, tid);
            __syncthreads();
#pragma unroll
            for (int ks = 0; ks < 2; ++ks) {
                short8 a[4], bfr[4];
#pragma unroll
                for (int m = 0; m < 4; ++m)
                    a[m] = *(const short8*)(As + (wm * 64 + m * 16 + fr) * 64 + ks * 32 + ko);
#pragma unroll
                for (int n = 0; n < 4; ++n)
                    bfr[n] = *(const short8*)(Bs + (wn * 64 + n * 16 + fr) * 64 + ks * 32 + ko);
#pragma unroll
                for (int m = 0; m < 4; ++m)
#pragma unroll
                    for (int n = 0; n < 4; ++n)
                        acc2[m][n] = __builtin_amdgcn_mfma_f32_16x16x32_bf16(
                            a[m], bfr[n], acc2[m][n], 0, 0, 0);
            }
        }
    }
    // u-term: A-frags from uLds
#pragma unroll 1
    for (int s2 = 0; s2 < 2; ++s2) {
        __syncthreads();
        stageB128(wTl + 32768, s2 * 64, Bs, tid);
        __syncthreads();
#pragma unroll
        for (int ks = 0; ks < 2; ++ks) {
            short8 a[4], bfr[4];
#pragma unroll
            for (int m = 0; m < 4; ++m)
                a[m] = *(const short8*)(uL + (wm * 64 + m * 16 + fr) * USTR + s2 * 64 + ks * 32 + ko);
#pragma unroll
            for (int n = 0; n < 4; ++n)
                bfr[n] = *(const short8*)(Bs + (wn * 64 + n * 16 + fr) * 64 + ks * 32 + ko);
#pragma unroll
            for (int m = 0; m < 4; ++m)
#pragma unroll
                for (int n = 0; n < 4; ++n)
                    acc2[m][n] = __builtin_amdgcn_mfma_f32_16x16x32_bf16(
                        a[m], bfr[n], acc2[m][n], 0, 0, 0);
        }
    }
    // ---- epilogue ----
#pragma unroll
    for (int m = 0; m < 4; ++m) {
        long gr0 = row0 + wm * 64 + m * 16 + ((lane >> 4) << 2);
        float4 dv;
        if (LAYER == 1) dv = *(const float4*)(dinv + gr0);
#pragma unroll
        for (int n = 0; n < 4; ++n) {
            int gj = wn * 64 + n * 16 + (lane & 15);
            bf16x4 tw;
#pragma unroll
            for (int qq = 0; qq < 4; ++qq) {
                long gr = gr0 + qq;
                float v = fmaxf(acc2[m][n][qq] + bias[gj], 0.0f);
                if (LAYER == 1) {
                    ybf[gr * D_ + gj] = f2bf(v);
                    tw[qq] = f2bf((&dv.x)[qq] * v);
                } else {
                    out[gr * 640 + gj] = v;
                }
            }
            if (LAYER == 1)
                *(bf16x4*)(pTout + (gr0 >> 9) * 65536 + (long)gj * 512 + (gr0 & 511)) = tw;
        }
    }
}

// ---------------- host ----------------

extern "C" void kernel_launch(void* const* d_in, const int* in_sizes, int n_in,
                              void* d_out, int out_size, void* d_ws, size_t ws_size,
                              hipStream_t stream) {
    const int* seq    = (const int*)d_in[0];
    const int* recd   = (const int*)d_in[1];
    const float* etab = (const float*)d_in[2];
    const float* rtab = (const float*)d_in[3];
    const float* w1   = (const float*)d_in[4];
    const float* b1   = (const float*)d_in[5];
    const float* w2   = (const float*)d_in[6];
    const float* b2   = (const float*)d_in[7];
    float* out = (float*)d_out;
    char* ws = (char*)d_ws;

    if (ws_size < 151470592u) return;

    unsigned short* Abf  = (unsigned short*)(ws);
    unsigned short* pTa  = (unsigned short*)(ws + 67108864);
    unsigned short* pTb  = (unsigned short*)(ws + 83886080);
    unsigned short* t1   = (unsigned short*)(ws + 100663296);
    unsigned short* rtb  = (unsigned short*)(ws + 117440512);   // 5,120,000 B
    float* rnorm         = (float*)(ws + 122683392);            // 262,144 B
    unsigned short* xbf  = (unsigned short*)(ws + 134217728);
    unsigned short* wT   = (unsigned short*)(ws + 150994944);
    float* psum = (float*)(ws + 151191552);
    float* pcnt = (float*)(ws + 151199744);
    float* dinv = (float*)(ws + 151208448);

    k_front<<<22114, 256, 0, stream>>>(recd, rtab, seq, etab, w1, w2,
                                       out, xbf, wT, rtb, rnorm);
    k_adj<<<1280, 256, 0, stream>>>(rtb, recd, rnorm, Abf, psum, pcnt);
    k_degtrs<<<1024, 256, 0, stream>>>(Abf, psum, pcnt, xbf, dinv, pTa);
    // layer 1
    k_sxm<<<256, 512, 0, stream>>>(Abf, dinv, pTa, t1, pTb);                    // t1 = Sx, pTb
    k_sxp<1><<<256, 512, 0, stream>>>(Abf, dinv, pTb, xbf, t1, wT, b1,
                                      xbf, pTa, nullptr);                       // y->xbf, pTa
    // layer 2
    k_sxm<<<256, 512, 0, stream>>>(Abf, dinv, pTa, t1, pTb);
    k_sxp<2><<<256, 512, 0, stream>>>(Abf, dinv, pTb, xbf, t1, wT + 49152, b2,
                                      nullptr, nullptr, out);
}